// Round 15
// baseline (936.492 us; speedup 1.0000x reference)
//
#include <hip/hip_runtime.h>
#include <hip/hip_bf16.h>

#define T_DIM 2048
#define N_DIM 256
#define K_DIM 256
#define C_DIM 40
#define CHUNK 32
#define NCHUNK 64                     // T_DIM / CHUNK
#define NSUPER (T_DIM * N_DIM / 64)   // 8192 supertiles of 64 rows
#define NTILES (T_DIM * N_DIM / 16)   // 32768 tiles of 16 rows

#define LOG2E_F 1.44269504088896340736f
#define LN2_F   0.69314718055994530942f
#define NEGBIG  (-1.0e30f)

typedef short bf16x8 __attribute__((ext_vector_type(8)));
typedef float f32x4  __attribute__((ext_vector_type(4)));

__device__ __forceinline__ float fexp2(float x) { return exp2f(x); }
__device__ __forceinline__ float flog2(float x) { return log2f(x); }
__device__ __forceinline__ float frcp(float x) { return __frcp_rn(x); }

__device__ __forceinline__ unsigned int pk2(float a, float b)
{
    __hip_bfloat162 h = __float22bfloat162_rn(make_float2(a, b));
    unsigned int r;
    __builtin_memcpy(&r, &h, sizeof(r));
    return r;
}

__device__ __forceinline__ uint4 pack8u(float4 lo, float4 hi)
{
    uint4 t;
    t.x = pk2(lo.x, lo.y);
    t.y = pk2(lo.z, lo.w);
    t.z = pk2(hi.x, hi.y);
    t.w = pk2(hi.z, hi.w);
    return t;
}

__device__ __forceinline__ bf16x8 as_bf16x8(uint4 u)
{
    bf16x8 r;
    __builtin_memcpy(&r, &u, sizeof(r));
    return r;
}

__device__ __forceinline__ unsigned short bf16r(float v)
{
    return (unsigned short)(pk2(v, 0.0f) & 0xffffu);
}

__device__ __forceinline__ float bl(unsigned int w) { return __uint_as_float(w << 16); }
__device__ __forceinline__ float bh(unsigned int w) { return __uint_as_float(w & 0xffff0000u); }

__device__ __forceinline__ float tanh5(float v)
{
    const float e = fexp2(fabsf(v) * (2.0f * LOG2E_F)); // e^(2|v|)
    const float t = 1.0f - 2.0f * frcp(e + 1.0f);       // tanh(|v|)
    return 5.0f * copysignf(t, v);
}

// ---------------------------------------------------------------------------
// K1 (REAL, R13 structure, unchanged): global_load_lds 2-phase pipeline.
// ---------------------------------------------------------------------------
__global__ __launch_bounds__(256, 2) void k1_gemm_tanh(
    const float* __restrict__ x, const float* __restrict__ W,
    const float* __restrict__ b, unsigned short* __restrict__ yb)
{
    __shared__ __align__(16) float xl[2][32 * 256];
    __shared__ __align__(16) float pl[2][12 * 64];

    const int tid  = threadIdx.x;
    const int wave = tid >> 6;
    const int lane = tid & 63;
    const int lr   = lane & 15;
    const int kg   = lane >> 4;
    const int mt   = wave & 1;
    const int kh   = wave >> 1;

    const float bc0 = b[lr];
    const float bc1 = b[16 + lr];
    const float bc2 = (lr < 8) ? b[32 + lr] : 0.0f;

    bf16x8 wf[4][3];
#pragma unroll
    for (int i = 0; i < 4; ++i) {
        const int ks = kh * 4 + i;
#pragma unroll
        for (int nt = 0; nt < 3; ++nt) {
            const int col = nt * 16 + lr;
            float4 lo = make_float4(0, 0, 0, 0), hi = lo;
            if (col < C_DIM) {
                const float* wp = W + (size_t)col * K_DIM + ks * 32 + kg * 8;
                lo = *(const float4*)wp;
                hi = *(const float4*)(wp + 4);
            }
            wf[i][nt] = as_bf16x8(pack8u(lo, hi));
        }
    }

#define STAGE(buf, st_)                                                        \
    {                                                                          \
        _Pragma("unroll")                                                      \
        for (int p = 0; p < 8; ++p) {                                          \
            const int r = wave * 8 + p;                                        \
            const float* gp = x + ((size_t)(st_) * 32 + r) * 256               \
                                + ((lane ^ (r & 7)) << 2);                     \
            __builtin_amdgcn_global_load_lds(                                  \
                (const __attribute__((address_space(1))) unsigned int*)gp,     \
                (__attribute__((address_space(3))) unsigned int*)&xl[buf][r * 256], \
                16, 0, 0);                                                     \
        }                                                                      \
    }

    const int rr = mt * 16 + lr;
    const int sw = lr & 7;

    int st = blockIdx.x;
    STAGE(0, st)
    asm volatile("s_waitcnt vmcnt(0)" ::: "memory");
    __builtin_amdgcn_s_barrier();

    int cur = 0;
#pragma unroll 1
    for (int t = 0; t < 32; ++t, st += 512) {
        if (t + 1 < 32) STAGE(cur ^ 1, st + 512)

        f32x4 af0, af1, af2;
        if (kh == 0) {
            af0 = (f32x4){bc0, bc0, bc0, bc0};
            af1 = (f32x4){bc1, bc1, bc1, bc1};
            af2 = (f32x4){bc2, bc2, bc2, bc2};
        } else {
            af0 = (f32x4){0.f, 0.f, 0.f, 0.f}; af1 = af0; af2 = af0;
        }
        const float* rowp = &xl[cur][rr * 256];
#pragma unroll
        for (int i = 0; i < 4; ++i) {
            const int u0 = (kh * 4 + i) * 8 + kg * 2;
            const float4 lo = *(const float4*)(rowp + ((u0 ^ sw) << 2));
            const float4 hi = *(const float4*)(rowp + (((u0 + 1) ^ sw) << 2));
            const bf16x8 a = as_bf16x8(pack8u(lo, hi));
            af0 = __builtin_amdgcn_mfma_f32_16x16x32_bf16(a, wf[i][0], af0, 0, 0, 0);
            af1 = __builtin_amdgcn_mfma_f32_16x16x32_bf16(a, wf[i][1], af1, 0, 0, 0);
            af2 = __builtin_amdgcn_mfma_f32_16x16x32_bf16(a, wf[i][2], af2, 0, 0, 0);
        }

        if (kh == 1) {
            float* p = &pl[mt][lane];
#pragma unroll
            for (int j = 0; j < 4; ++j) p[j * 64]       = af0[j];
#pragma unroll
            for (int j = 0; j < 4; ++j) p[(4 + j) * 64] = af1[j];
#pragma unroll
            for (int j = 0; j < 4; ++j) p[(8 + j) * 64] = af2[j];
        }
        asm volatile("s_waitcnt lgkmcnt(0)" ::: "memory");
        __builtin_amdgcn_s_barrier();

        if (kh == 0) {
            const float* p = &pl[mt][lane];
            unsigned short* yr =
                yb + ((size_t)st * 32 + mt * 16 + kg * 4) * C_DIM;
#pragma unroll
            for (int r = 0; r < 4; ++r) {
                yr[r * C_DIM + lr]      = bf16r(tanh5(af0[r] + p[r * 64]));
                yr[r * C_DIM + 16 + lr] = bf16r(tanh5(af1[r] + p[(4 + r) * 64]));
                if (lr < 8)
                    yr[r * C_DIM + 32 + lr] = bf16r(tanh5(af2[r] + p[(8 + r) * 64]));
            }
            asm volatile("s_waitcnt vmcnt(12)" ::: "memory");
        } else {
            asm volatile("s_waitcnt vmcnt(0)" ::: "memory");
        }
        __builtin_amdgcn_s_barrier();
        cur ^= 1;
    }
#undef STAGE
}

// ---------------------------------------------------------------------------
// k1a: R13 structure, REPEAT x2, output to dead scratch. >320us => shows in
// counter table. Reads: OccupancyPercent / FETCH_SIZE / VALUBusy / MfmaUtil.
// ---------------------------------------------------------------------------
__global__ __launch_bounds__(256, 2) void k1a_glds_rep2(
    const float* __restrict__ x, const float* __restrict__ W,
    const float* __restrict__ b, unsigned short* __restrict__ yb)
{
    __shared__ __align__(16) float xl[2][32 * 256];
    __shared__ __align__(16) float pl[2][12 * 64];

    const int tid  = threadIdx.x;
    const int wave = tid >> 6;
    const int lane = tid & 63;
    const int lr   = lane & 15;
    const int kg   = lane >> 4;
    const int mt   = wave & 1;
    const int kh   = wave >> 1;

    const float bc0 = b[lr];
    const float bc1 = b[16 + lr];
    const float bc2 = (lr < 8) ? b[32 + lr] : 0.0f;

    bf16x8 wf[4][3];
#pragma unroll
    for (int i = 0; i < 4; ++i) {
        const int ks = kh * 4 + i;
#pragma unroll
        for (int nt = 0; nt < 3; ++nt) {
            const int col = nt * 16 + lr;
            float4 lo = make_float4(0, 0, 0, 0), hi = lo;
            if (col < C_DIM) {
                const float* wp = W + (size_t)col * K_DIM + ks * 32 + kg * 8;
                lo = *(const float4*)wp;
                hi = *(const float4*)(wp + 4);
            }
            wf[i][nt] = as_bf16x8(pack8u(lo, hi));
        }
    }

#define STAGE(buf, st_)                                                        \
    {                                                                          \
        _Pragma("unroll")                                                      \
        for (int p = 0; p < 8; ++p) {                                          \
            const int r = wave * 8 + p;                                        \
            const float* gp = x + ((size_t)(st_) * 32 + r) * 256               \
                                + ((lane ^ (r & 7)) << 2);                     \
            __builtin_amdgcn_global_load_lds(                                  \
                (const __attribute__((address_space(1))) unsigned int*)gp,     \
                (__attribute__((address_space(3))) unsigned int*)&xl[buf][r * 256], \
                16, 0, 0);                                                     \
        }                                                                      \
    }

    const int rr = mt * 16 + lr;
    const int sw = lr & 7;

#pragma unroll 1
    for (int rep = 0; rep < 2; ++rep) {
        int st = blockIdx.x;
        STAGE(0, st)
        asm volatile("s_waitcnt vmcnt(0)" ::: "memory");
        __builtin_amdgcn_s_barrier();

        int cur = 0;
#pragma unroll 1
        for (int t = 0; t < 32; ++t, st += 512) {
            if (t + 1 < 32) STAGE(cur ^ 1, st + 512)

            f32x4 af0, af1, af2;
            if (kh == 0) {
                af0 = (f32x4){bc0, bc0, bc0, bc0};
                af1 = (f32x4){bc1, bc1, bc1, bc1};
                af2 = (f32x4){bc2, bc2, bc2, bc2};
            } else {
                af0 = (f32x4){0.f, 0.f, 0.f, 0.f}; af1 = af0; af2 = af0;
            }
            const float* rowp = &xl[cur][rr * 256];
#pragma unroll
            for (int i = 0; i < 4; ++i) {
                const int u0 = (kh * 4 + i) * 8 + kg * 2;
                const float4 lo = *(const float4*)(rowp + ((u0 ^ sw) << 2));
                const float4 hi = *(const float4*)(rowp + (((u0 + 1) ^ sw) << 2));
                const bf16x8 a = as_bf16x8(pack8u(lo, hi));
                af0 = __builtin_amdgcn_mfma_f32_16x16x32_bf16(a, wf[i][0], af0, 0, 0, 0);
                af1 = __builtin_amdgcn_mfma_f32_16x16x32_bf16(a, wf[i][1], af1, 0, 0, 0);
                af2 = __builtin_amdgcn_mfma_f32_16x16x32_bf16(a, wf[i][2], af2, 0, 0, 0);
            }

            if (kh == 1) {
                float* p = &pl[mt][lane];
#pragma unroll
                for (int j = 0; j < 4; ++j) p[j * 64]       = af0[j];
#pragma unroll
                for (int j = 0; j < 4; ++j) p[(4 + j) * 64] = af1[j];
#pragma unroll
                for (int j = 0; j < 4; ++j) p[(8 + j) * 64] = af2[j];
            }
            asm volatile("s_waitcnt lgkmcnt(0)" ::: "memory");
            __builtin_amdgcn_s_barrier();

            if (kh == 0) {
                const float* p = &pl[mt][lane];
                unsigned short* yr =
                    yb + ((size_t)st * 32 + mt * 16 + kg * 4) * C_DIM;
#pragma unroll
                for (int r = 0; r < 4; ++r) {
                    yr[r * C_DIM + lr]      = bf16r(tanh5(af0[r] + p[r * 64]));
                    yr[r * C_DIM + 16 + lr] = bf16r(tanh5(af1[r] + p[(4 + r) * 64]));
                    if (lr < 8)
                        yr[r * C_DIM + 32 + lr] = bf16r(tanh5(af2[r] + p[(8 + r) * 64]));
                }
                asm volatile("s_waitcnt vmcnt(12)" ::: "memory");
            } else {
                asm volatile("s_waitcnt vmcnt(0)" ::: "memory");
            }
            __builtin_amdgcn_s_barrier();
            cur ^= 1;
        }
    }
#undef STAGE
}

// ---------------------------------------------------------------------------
// k1b: R14 direct-load structure, REPEAT x2, scratch output.
// Reads: VGPR_Count (did lv[16] fit under the 128 cap?), occupancy.
// ---------------------------------------------------------------------------
__global__ __launch_bounds__(512, 4) void k1b_direct_rep2(
    const float* __restrict__ x, const float* __restrict__ W,
    const float* __restrict__ b, unsigned short* __restrict__ yb)
{
    __shared__ __align__(16) uint4 wlds[24 * 64];

    const int tid = threadIdx.x;
#pragma unroll
    for (int p = 0; p < 3; ++p) {
        const int f    = p * 512 + tid;
        const int l    = f & 63;
        const int frag = f >> 6;
        const int nt   = frag % 3;
        const int ks   = frag / 3;
        const int col  = nt * 16 + (l & 15);
        const int kg   = l >> 4;
        float4 lo = make_float4(0, 0, 0, 0), hi = lo;
        if (col < C_DIM) {
            lo = *(const float4*)(W + (size_t)col * K_DIM + ks * 32 + kg * 4);
            hi = *(const float4*)(W + (size_t)col * K_DIM + ks * 32 + 16 + kg * 4);
        }
        wlds[frag * 64 + l] = pack8u(lo, hi);
    }
    __syncthreads();

    const int wave = tid >> 6;
    const int lane = tid & 63;
    const int lr   = lane & 15;
    const int kg   = lane >> 4;

    const float bc0 = b[lr];
    const float bc1 = b[16 + lr];
    const float bc2 = (lr < 8) ? b[32 + lr] : 0.0f;

    const int gw = blockIdx.x * 8 + wave;

#pragma unroll 1
    for (int rep = 0; rep < 2; ++rep) {
#pragma unroll 1
        for (int tile = gw; tile < NTILES; tile += 4096) {
            const float4* __restrict__ xp4 =
                (const float4*)(x + ((size_t)tile * 16 + lr) * K_DIM) + kg;

            float4 lv[16];
#pragma unroll
            for (int i = 0; i < 8; ++i) {
                lv[2 * i]     = xp4[i * 8];
                lv[2 * i + 1] = xp4[i * 8 + 4];
            }
            __builtin_amdgcn_sched_barrier(0);

            f32x4 af0 = {bc0, bc0, bc0, bc0};
            f32x4 af1 = {bc1, bc1, bc1, bc1};
            f32x4 af2 = {bc2, bc2, bc2, bc2};

#pragma unroll
            for (int ks = 0; ks < 8; ++ks) {
                const bf16x8 a  = as_bf16x8(pack8u(lv[2 * ks], lv[2 * ks + 1]));
                const bf16x8 w0 = *(const bf16x8*)&wlds[(ks * 3 + 0) * 64 + lane];
                const bf16x8 w1 = *(const bf16x8*)&wlds[(ks * 3 + 1) * 64 + lane];
                const bf16x8 w2 = *(const bf16x8*)&wlds[(ks * 3 + 2) * 64 + lane];
                af0 = __builtin_amdgcn_mfma_f32_16x16x32_bf16(a, w0, af0, 0, 0, 0);
                af1 = __builtin_amdgcn_mfma_f32_16x16x32_bf16(a, w1, af1, 0, 0, 0);
                af2 = __builtin_amdgcn_mfma_f32_16x16x32_bf16(a, w2, af2, 0, 0, 0);
            }

            unsigned short* yr = yb + ((size_t)tile * 16 + kg * 4) * C_DIM;
#pragma unroll
            for (int r = 0; r < 4; ++r) {
                yr[r * C_DIM + lr]      = bf16r(tanh5(af0[r]));
                yr[r * C_DIM + 16 + lr] = bf16r(tanh5(af1[r]));
                if (lr < 8)
                    yr[r * C_DIM + 32 + lr] = bf16r(tanh5(af2[r]));
            }
        }
    }
}

// ---------------------------------------------------------------------------
// k1c: probe-shaped CONTIGUOUS reads + same pack/MFMA/tanh/scattered-store
// compute attached (junk math, scratch output, not validated). REPEAT x2.
// Separates "read shape" from "attached compute" cost.
// ---------------------------------------------------------------------------
__global__ __launch_bounds__(512, 4) void k1c_contig_rep2(
    const float* __restrict__ x, unsigned short* __restrict__ scr)
{
    const int tid  = threadIdx.x;
    const int wave = tid >> 6;
    const int lane = tid & 63;
    const int lr   = lane & 15;
    const int kg   = lane >> 4;

#pragma unroll 1
    for (int rep = 0; rep < 2; ++rep) {
#pragma unroll 1
        for (int st = blockIdx.x; st < NSUPER; st += 1024) {
            const float4* __restrict__ xg4 =
                (const float4*)(x + (size_t)st * 64 * K_DIM);
            float4 v[8];
#pragma unroll
            for (int p = 0; p < 8; ++p) v[p] = xg4[p * 512 + tid];
            __builtin_amdgcn_sched_barrier(0);

            bf16x8 a[4];
#pragma unroll
            for (int j = 0; j < 4; ++j)
                a[j] = as_bf16x8(pack8u(v[2 * j], v[2 * j + 1]));

            f32x4 af0 = {0.f, 0.f, 0.f, 0.f}, af1 = af0, af2 = af0;
#pragma unroll
            for (int ks = 0; ks < 8; ++ks) {
                const bf16x8 aa = a[ks & 3];
                const bf16x8 ab = a[(ks + 1) & 3];
                af0 = __builtin_amdgcn_mfma_f32_16x16x32_bf16(aa, ab, af0, 0, 0, 0);
                af1 = __builtin_amdgcn_mfma_f32_16x16x32_bf16(ab, aa, af1, 0, 0, 0);
                af2 = __builtin_amdgcn_mfma_f32_16x16x32_bf16(aa, aa, af2, 0, 0, 0);
            }

            unsigned short* yr =
                scr + (((size_t)st * 4 + wave) * 16 + kg * 4) * C_DIM;
#pragma unroll
            for (int r = 0; r < 4; ++r) {
                yr[r * C_DIM + lr]      = bf16r(tanh5(af0[r]));
                yr[r * C_DIM + 16 + lr] = bf16r(tanh5(af1[r]));
                if (lr < 8)
                    yr[r * C_DIM + 32 + lr] = bf16r(tanh5(af2[r]));
            }
        }
    }
}

// ---------------------------------------------------------------------------
// K2/K3/K4: unchanged from R13.
// ---------------------------------------------------------------------------
__global__ __launch_bounds__(256) void k2_chunks(
    const unsigned short* __restrict__ yb, float* __restrict__ cmat)
{
    const int tid  = threadIdx.x;
    const int wave = tid >> 6;
    const int lane = tid & 63;
    const int task = lane >> 3;
    const int c    = lane & 7;
    const int g    = blockIdx.x & (NCHUNK - 1);
    const int n    = ((blockIdx.x >> 6) << 5) + (wave << 3) + task;

    float col[8];
#pragma unroll
    for (int j = 0; j < 8; ++j) col[j] = (j == c) ? 0.0f : NEGBIG;

    const unsigned short* __restrict__ yp =
        yb + ((size_t)(g * CHUNK) * N_DIM + (size_t)n) * C_DIM;

#pragma unroll 1
    for (int s = 0; s < CHUNK; ++s) {
        float sc[C_DIM];
        const uint4* p4 = (const uint4*)yp;
#pragma unroll
        for (int q = 0; q < 5; ++q) {
            const uint4 u = p4[q];
            sc[8 * q + 0] = bl(u.x) * LOG2E_F;
            sc[8 * q + 1] = bh(u.x) * LOG2E_F;
            sc[8 * q + 2] = bl(u.y) * LOG2E_F;
            sc[8 * q + 3] = bh(u.y) * LOG2E_F;
            sc[8 * q + 4] = bl(u.z) * LOG2E_F;
            sc[8 * q + 5] = bh(u.z) * LOG2E_F;
            sc[8 * q + 6] = bl(u.w) * LOG2E_F;
            sc[8 * q + 7] = bh(u.w) * LOG2E_F;
        }
        float nc[8];
#pragma unroll
        for (int d = 0; d < 4; ++d) {
            float tv[8];
#pragma unroll
            for (int j = 0; j < 8; ++j) tv[j] = sc[d * 8 + j] + col[j];
            float m = tv[0];
#pragma unroll
            for (int j = 1; j < 8; ++j) m = fmaxf(m, tv[j]);
            float ss = 0.0f;
#pragma unroll
            for (int j = 0; j < 8; ++j) ss += fexp2(tv[j] - m);
            nc[d] = m + flog2(ss);
        }
#pragma unroll
        for (int i = 0; i < 4; ++i) {
            const float a  = sc[32 + i] + col[i];
            const float bb = sc[36 + i] + col[i + 4];
            const float m  = fmaxf(a, bb);
            const float ss = fexp2(a - m) + fexp2(bb - m);
            nc[4 + i] = m + flog2(ss);
        }
#pragma unroll
        for (int j = 0; j < 8; ++j) col[j] = nc[j];
        yp += (size_t)N_DIM * C_DIM;
    }
    float* __restrict__ op = cmat + (((size_t)g * 8 + c) * N_DIM + n) * 8;
#pragma unroll
    for (int j = 0; j < 8; ++j) op[j] = col[j];
}

__global__ __launch_bounds__(256) void k3_combine(
    const float* __restrict__ cmat, float* __restrict__ corr)
{
    const int tid = threadIdx.x;
    const int d   = tid & 7;
    const int n   = blockIdx.x * 32 + (tid >> 3);

    float v[8];
#pragma unroll
    for (int j = 0; j < 8; ++j) v[j] = 0.0f;

#pragma unroll 1
    for (int g = 0; g < NCHUNK; ++g) {
        const float* mg = cmat + ((size_t)g * 8 * N_DIM + n) * 8 + d;
        float mm[8];
#pragma unroll
        for (int j = 0; j < 8; ++j) mm[j] = mg[(size_t)j * N_DIM * 8];
        float tv[8];
#pragma unroll
        for (int j = 0; j < 8; ++j) tv[j] = mm[j] + v[j];
        float m = tv[0];
#pragma unroll
        for (int j = 1; j < 8; ++j) m = fmaxf(m, tv[j]);
        float ss = 0.0f;
#pragma unroll
        for (int j = 0; j < 8; ++j) ss += fexp2(tv[j] - m);
        const float nv = m + flog2(ss);
#pragma unroll
        for (int j = 0; j < 8; ++j) v[j] = __shfl(nv, j, 8);
    }
    float m = v[0];
#pragma unroll
    for (int j = 1; j < 8; ++j) m = fmaxf(m, v[j]);
    float ss = 0.0f;
#pragma unroll
    for (int j = 0; j < 8; ++j) ss += fexp2(v[j] - m);
    const float lz2 = m + flog2(ss);
    if (d == 0) corr[n] = lz2 * LN2_F / (float)T_DIM;
}

__global__ __launch_bounds__(256) void k4_final(
    const unsigned short* __restrict__ yb, const float* __restrict__ corr,
    float* __restrict__ out)
{
    const int i = blockIdx.x * 256 + threadIdx.x;
    const uint4 u = ((const uint4*)yb)[i];
    const float cr = corr[(i / 5) & (N_DIM - 1)];
    float4 o0, o1;
    o0.x = bl(u.x) - cr; o0.y = bh(u.x) - cr;
    o0.z = bl(u.y) - cr; o0.w = bh(u.y) - cr;
    o1.x = bl(u.z) - cr; o1.y = bh(u.z) - cr;
    o1.z = bl(u.w) - cr; o1.w = bh(u.w) - cr;
    float4* o4 = (float4*)out;
    o4[i * 2]     = o0;
    o4[i * 2 + 1] = o1;
}

// ---------------------------------------------------------------------------
extern "C" void kernel_launch(void* const* d_in, const int* in_sizes, int n_in,
                              void* d_out, int out_size, void* d_ws, size_t ws_size,
                              hipStream_t stream)
{
    const float* x = (const float*)d_in[0];
    const float* W = (const float*)d_in[1];
    const float* b = (const float*)d_in[2];
    float* out = (float*)d_out;

    unsigned short* ybf = (unsigned short*)d_ws;              // 40 MB bf16 y
    float* cmat = (float*)((char*)d_ws + (48u << 20));        // 4 MB
    float* corr = cmat + (size_t)NCHUNK * 8 * N_DIM * 8;
    unsigned short* scrA = (unsigned short*)((char*)d_ws + (128u << 20));
    unsigned short* scrB = (unsigned short*)((char*)d_ws + (192u << 20));
    unsigned short* scrC = (unsigned short*)((char*)d_ws + (256u << 20));

    // real pipeline (R13, best-known: 246.6 us)
    hipLaunchKernelGGL(k1_gemm_tanh, dim3(512),  dim3(256), 0, stream, x, W, b, ybf);
    hipLaunchKernelGGL(k2_chunks,    dim3(512),  dim3(256), 0, stream, ybf, cmat);
    hipLaunchKernelGGL(k3_combine,   dim3(8),    dim3(256), 0, stream, cmat, corr);
    hipLaunchKernelGGL(k4_final,     dim3(T_DIM * N_DIM * C_DIM / 8 / 256),
                       dim3(256), 0, stream, ybf, corr, out);

    // instrumentation (rep x2 so they outlast the 315us poison-fills and
    // surface in the top-5 counter table; outputs go to dead ws scratch)
    hipLaunchKernelGGL(k1a_glds_rep2,  dim3(512),  dim3(256), 0, stream, x, W, b, scrA);
    hipLaunchKernelGGL(k1b_direct_rep2,dim3(512),  dim3(512), 0, stream, x, W, b, scrB);
    hipLaunchKernelGGL(k1c_contig_rep2,dim3(1024), dim3(512), 0, stream, x, scrC);
}

// Round 16
// 366.957 us; speedup vs baseline: 2.5521x; 2.5521x over previous
//
#include <hip/hip_runtime.h>
#include <hip/hip_bf16.h>

#define T_DIM 2048
#define N_DIM 256
#define K_DIM 256
#define C_DIM 40
#define CHUNK 16
#define NCHUNK 128                    // T_DIM / CHUNK
#define NT32 (T_DIM * N_DIM / 32)     // 16384 supertiles of 32 rows

#define LOG2E_F 1.44269504088896340736f
#define LN2_F   0.69314718055994530942f
#define NEGBIG  (-1.0e30f)

typedef short bf16x8 __attribute__((ext_vector_type(8)));
typedef float f32x4  __attribute__((ext_vector_type(4)));

__device__ __forceinline__ float fexp2(float x) { return exp2f(x); }
__device__ __forceinline__ float flog2(float x) { return log2f(x); }
__device__ __forceinline__ float frcp(float x) { return __frcp_rn(x); }

__device__ __forceinline__ unsigned int pk2(float a, float b)
{
    __hip_bfloat162 h = __float22bfloat162_rn(make_float2(a, b));
    unsigned int r;
    __builtin_memcpy(&r, &h, sizeof(r));
    return r;
}

__device__ __forceinline__ uint4 pack8u(float4 lo, float4 hi)
{
    uint4 t;
    t.x = pk2(lo.x, lo.y);
    t.y = pk2(lo.z, lo.w);
    t.z = pk2(hi.x, hi.y);
    t.w = pk2(hi.z, hi.w);
    return t;
}

__device__ __forceinline__ bf16x8 as_bf16x8(uint4 u)
{
    bf16x8 r;
    __builtin_memcpy(&r, &u, sizeof(r));
    return r;
}

__device__ __forceinline__ unsigned short bf16r(float v)
{
    return (unsigned short)(pk2(v, 0.0f) & 0xffffu);
}

__device__ __forceinline__ float bl(unsigned int w) { return __uint_as_float(w << 16); }
__device__ __forceinline__ float bh(unsigned int w) { return __uint_as_float(w & 0xffff0000u); }

__device__ __forceinline__ float tanh5(float v)
{
    const float e = fexp2(fabsf(v) * (2.0f * LOG2E_F)); // e^(2|v|)
    const float t = 1.0f - 2.0f * frcp(e + 1.0f);       // tanh(|v|)
    return 5.0f * copysignf(t, v);
}

// ---------------------------------------------------------------------------
// K1: yb[row][c] = bf16(5*tanh(dot(x[row], W[c]) + b[c]))  via bf16 MFMA.
// R15 diagnostics: K1(R13-shape) <= ~155us; probe-shaped-with-compute at 32
// waves/CU also <= ~155us => per-CU wave/block concurrency is the BW lever,
// not structure. This version keeps R13's counted-vmcnt pipeline but stages
// K-HALVES (32 rows x 128 f32 = 16KB; dbuf 2x16 + 6 pl = 38KB LDS) =>
// 4 blocks/CU = 16 waves/CU (2x R13). Waves = 2 mt x 2 kq; af accumulates
// across the two halves of each supertile; epilogue once per supertile.
// Both-sides XOR unit-swizzle (write src unit = c ^ (row&7), read unit =
// u ^ (lr&7)). Grid 1024 = exactly 4 blocks/CU resident, 16 supertiles each.
// ---------------------------------------------------------------------------
__global__ __launch_bounds__(256, 4) void k1_gemm_tanh(
    const float* __restrict__ x, const float* __restrict__ W,
    const float* __restrict__ b, unsigned short* __restrict__ yb)
{
    __shared__ __align__(16) float xl[2][32 * 128];   // 2 x 16KB fp32 half-tiles
    __shared__ __align__(16) float pl[2][12 * 64];    // 6KB partials [mt][j*64+lane]

    const int tid  = threadIdx.x;
    const int wave = tid >> 6;
    const int lane = tid & 63;
    const int lr   = lane & 15;
    const int kg   = lane >> 4;
    const int mt   = wave & 1;    // M-tile: rows mt*16 .. +16
    const int kq   = wave >> 1;   // K-quarter pair: ks_local = kq*2 + i

    const float bc0 = b[lr];
    const float bc1 = b[16 + lr];
    const float bc2 = (lr < 8) ? b[32 + lr] : 0.0f;

    // ---- W fragments: ks_global = h*4 + kq*2 + i  (48 VGPR) ----
    bf16x8 wf[2][2][3];
#pragma unroll
    for (int h = 0; h < 2; ++h) {
#pragma unroll
        for (int i = 0; i < 2; ++i) {
            const int ks = h * 4 + kq * 2 + i;
#pragma unroll
            for (int nt = 0; nt < 3; ++nt) {
                const int col = nt * 16 + lr;
                float4 lo = make_float4(0, 0, 0, 0), hi = lo;
                if (col < C_DIM) {
                    const float* wp = W + (size_t)col * K_DIM + ks * 32 + kg * 8;
                    lo = *(const float4*)wp;
                    hi = *(const float4*)(wp + 4);
                }
                wf[h][i][nt] = as_bf16x8(pack8u(lo, hi));
            }
        }
    }

    // stage half h of supertile st_: 32 rows x 128 f32; each wave 4 insts,
    // each inst = 2 rows (64 lanes x 16B = 1KB). LDS write is linear
    // (base + lane*16); read swizzle is compensated on the GLOBAL src unit:
    // lane l covers row r = rbase+(l>>5), row-unit (l&31), src unit
    // (l&31) ^ (r&7)  =>  LDS[r][c] holds x[r][c ^ (r&7)].
#define STAGE(buf, st_, h_)                                                    \
    {                                                                          \
        _Pragma("unroll")                                                      \
        for (int p = 0; p < 4; ++p) {                                          \
            const int rbase = wave * 8 + p * 2;                                \
            const int r     = rbase + (lane >> 5);                             \
            const int cu    = (lane & 31) ^ (r & 7);                           \
            const float* gp = x + ((size_t)(st_) * 32 + r) * 256               \
                                + (h_) * 128 + (cu << 2);                      \
            __builtin_amdgcn_global_load_lds(                                  \
                (const __attribute__((address_space(1))) unsigned int*)gp,     \
                (__attribute__((address_space(3))) unsigned int*)&xl[buf][rbase * 128], \
                16, 0, 0);                                                     \
        }                                                                      \
    }

    const int rr = mt * 16 + lr;       // row within supertile
    const int sw = lr & 7;             // read-side unit swizzle ( == rr&7 )

    int st = blockIdx.x;               // 16 supertiles: st, st+1024, ...
    STAGE(0, st, 0)
    asm volatile("s_waitcnt vmcnt(0)" ::: "memory");
    __builtin_amdgcn_s_barrier();

    f32x4 af0, af1, af2;
    int cur = 0;
#pragma unroll 1
    for (int t = 0; t < 32; ++t) {
        const int h = t & 1;
        if (t + 1 < 32) {
            if (h == 0) STAGE(cur ^ 1, st, 1)
            else        STAGE(cur ^ 1, st + 1024, 0)
        }

        if (h == 0) {
            if (kq == 0) {
                af0 = (f32x4){bc0, bc0, bc0, bc0};
                af1 = (f32x4){bc1, bc1, bc1, bc1};
                af2 = (f32x4){bc2, bc2, bc2, bc2};
            } else {
                af0 = (f32x4){0.f, 0.f, 0.f, 0.f}; af1 = af0; af2 = af0;
            }
        }

        const float* rowp = &xl[cur][rr * 128];
#pragma unroll
        for (int i = 0; i < 2; ++i) {
            const int u0 = (kq * 2 + i) * 8 + kg * 2;   // 16B-unit in half-row
            const float4 lo = *(const float4*)(rowp + ((u0 ^ sw) << 2));
            const float4 hi = *(const float4*)(rowp + (((u0 + 1) ^ sw) << 2));
            const bf16x8 a = as_bf16x8(pack8u(lo, hi));
            af0 = __builtin_amdgcn_mfma_f32_16x16x32_bf16(a, wf[h][i][0], af0, 0, 0, 0);
            af1 = __builtin_amdgcn_mfma_f32_16x16x32_bf16(a, wf[h][i][1], af1, 0, 0, 0);
            af2 = __builtin_amdgcn_mfma_f32_16x16x32_bf16(a, wf[h][i][2], af2, 0, 0, 0);
        }

        if (h == 1) {
            if (kq == 1) {       // publish upper-K partials
                float* p = &pl[mt][lane];
#pragma unroll
                for (int j = 0; j < 4; ++j) p[j * 64]       = af0[j];
#pragma unroll
                for (int j = 0; j < 4; ++j) p[(4 + j) * 64] = af1[j];
#pragma unroll
                for (int j = 0; j < 4; ++j) p[(8 + j) * 64] = af2[j];
            }
            asm volatile("s_waitcnt lgkmcnt(0)" ::: "memory");
            __builtin_amdgcn_s_barrier();      // B1: pl visible; xl reads done

            if (kq == 0) {       // combine + epilogue (12 stores)
                const float* p = &pl[mt][lane];
                unsigned short* yr =
                    yb + ((size_t)st * 32 + mt * 16 + kg * 4) * C_DIM;
#pragma unroll
                for (int r = 0; r < 4; ++r) {
                    yr[r * C_DIM + lr]      = bf16r(tanh5(af0[r] + p[r * 64]));
                    yr[r * C_DIM + 16 + lr] = bf16r(tanh5(af1[r] + p[(4 + r) * 64]));
                    if (lr < 8)
                        yr[r * C_DIM + 32 + lr] = bf16r(tanh5(af2[r] + p[(8 + r) * 64]));
                }
                // 4 gloads are OLDER than the 12 stores; vmcnt(12) forces the
                // gloads complete while letting stores drain in background.
                asm volatile("s_waitcnt vmcnt(12)" ::: "memory");
            } else {
                asm volatile("s_waitcnt vmcnt(0)" ::: "memory");
            }
            __builtin_amdgcn_s_barrier();      // B2: next half staged
            st += 1024;
        } else {
            asm volatile("s_waitcnt lgkmcnt(0)" ::: "memory");
            asm volatile("s_waitcnt vmcnt(0)" ::: "memory");
            __builtin_amdgcn_s_barrier();      // half boundary: next half staged
        }
        cur ^= 1;
    }
#undef STAGE
}

// ---------------------------------------------------------------------------
// K2: per (chain n, chunk g) propagate the 8x8 log-semiring matrix through
// 16 steps (was 32; 128 chunks => 1024 blocks = 16 waves/CU, 2x parallelism).
// y bf16 (5 x uint4 loads, shift-unpack). Base-2 domain.
// ---------------------------------------------------------------------------
__global__ __launch_bounds__(256) void k2_chunks(
    const unsigned short* __restrict__ yb, float* __restrict__ cmat)
{
    const int tid  = threadIdx.x;
    const int wave = tid >> 6;
    const int lane = tid & 63;
    const int task = lane >> 3;   // 8 tasks per wave
    const int c    = lane & 7;    // column owned by this lane
    const int g    = blockIdx.x & (NCHUNK - 1);
    const int n    = ((blockIdx.x >> 7) << 5) + (wave << 3) + task;

    float col[8];
#pragma unroll
    for (int j = 0; j < 8; ++j) col[j] = (j == c) ? 0.0f : NEGBIG;

    const unsigned short* __restrict__ yp =
        yb + ((size_t)(g * CHUNK) * N_DIM + (size_t)n) * C_DIM;

#pragma unroll 1
    for (int s = 0; s < CHUNK; ++s) {
        float sc[C_DIM];
        const uint4* p4 = (const uint4*)yp;
#pragma unroll
        for (int q = 0; q < 5; ++q) {
            const uint4 u = p4[q];
            sc[8 * q + 0] = bl(u.x) * LOG2E_F;
            sc[8 * q + 1] = bh(u.x) * LOG2E_F;
            sc[8 * q + 2] = bl(u.y) * LOG2E_F;
            sc[8 * q + 3] = bh(u.y) * LOG2E_F;
            sc[8 * q + 4] = bl(u.z) * LOG2E_F;
            sc[8 * q + 5] = bh(u.z) * LOG2E_F;
            sc[8 * q + 6] = bl(u.w) * LOG2E_F;
            sc[8 * q + 7] = bh(u.w) * LOG2E_F;
        }
        float nc[8];
#pragma unroll
        for (int d = 0; d < 4; ++d) {          // dense rows: lse over 8
            float tv[8];
#pragma unroll
            for (int j = 0; j < 8; ++j) tv[j] = sc[d * 8 + j] + col[j];
            float m = tv[0];
#pragma unroll
            for (int j = 1; j < 8; ++j) m = fmaxf(m, tv[j]);
            float ss = 0.0f;
#pragma unroll
            for (int j = 0; j < 8; ++j) ss += fexp2(tv[j] - m);
            nc[d] = m + flog2(ss);
        }
#pragma unroll
        for (int i = 0; i < 4; ++i) {          // sparse rows: logaddexp of 2
            const float a  = sc[32 + i] + col[i];
            const float bb = sc[36 + i] + col[i + 4];
            const float m  = fmaxf(a, bb);
            const float ss = fexp2(a - m) + fexp2(bb - m);
            nc[4 + i] = m + flog2(ss);
        }
#pragma unroll
        for (int j = 0; j < 8; ++j) col[j] = nc[j];
        yp += (size_t)N_DIM * C_DIM;
    }
    // store M[j][c] at cmat[((g*8 + c)*N_DIM + n)*8 + j]
    float* __restrict__ op = cmat + (((size_t)g * 8 + c) * N_DIM + n) * 8;
#pragma unroll
    for (int j = 0; j < 8; ++j) op[j] = col[j];
}

// ---------------------------------------------------------------------------
// K3: per chain, fold the 128 chunk matrices into logZ.
// ---------------------------------------------------------------------------
__global__ __launch_bounds__(256) void k3_combine(
    const float* __restrict__ cmat, float* __restrict__ corr)
{
    const int tid = threadIdx.x;
    const int d   = tid & 7;
    const int n   = blockIdx.x * 32 + (tid >> 3);

    float v[8];
#pragma unroll
    for (int j = 0; j < 8; ++j) v[j] = 0.0f;

#pragma unroll 1
    for (int g = 0; g < NCHUNK; ++g) {
        const float* mg = cmat + ((size_t)g * 8 * N_DIM + n) * 8 + d;
        float mm[8];
#pragma unroll
        for (int j = 0; j < 8; ++j) mm[j] = mg[(size_t)j * N_DIM * 8];
        float tv[8];
#pragma unroll
        for (int j = 0; j < 8; ++j) tv[j] = mm[j] + v[j];
        float m = tv[0];
#pragma unroll
        for (int j = 1; j < 8; ++j) m = fmaxf(m, tv[j]);
        float ss = 0.0f;
#pragma unroll
        for (int j = 0; j < 8; ++j) ss += fexp2(tv[j] - m);
        const float nv = m + flog2(ss);
#pragma unroll
        for (int j = 0; j < 8; ++j) v[j] = __shfl(nv, j, 8);
    }
    float m = v[0];
#pragma unroll
    for (int j = 1; j < 8; ++j) m = fmaxf(m, v[j]);
    float ss = 0.0f;
#pragma unroll
    for (int j = 0; j < 8; ++j) ss += fexp2(v[j] - m);
    const float lz2 = m + flog2(ss);                 // base-2 logZ
    if (d == 0) corr[n] = lz2 * LN2_F / (float)T_DIM;
}

// ---------------------------------------------------------------------------
// K4: out[t][n][c] = f32(yb[t][n][c]) - corr[n]
// ---------------------------------------------------------------------------
__global__ __launch_bounds__(256) void k4_final(
    const unsigned short* __restrict__ yb, const float* __restrict__ corr,
    float* __restrict__ out)
{
    const int i = blockIdx.x * 256 + threadIdx.x;    // 8-elem group index
    const uint4 u = ((const uint4*)yb)[i];
    const float cr = corr[(i / 5) & (N_DIM - 1)];    // 5 groups per row
    float4 o0, o1;
    o0.x = bl(u.x) - cr; o0.y = bh(u.x) - cr;
    o0.z = bl(u.y) - cr; o0.w = bh(u.y) - cr;
    o1.x = bl(u.z) - cr; o1.y = bh(u.z) - cr;
    o1.z = bl(u.w) - cr; o1.w = bh(u.w) - cr;
    float4* o4 = (float4*)out;
    o4[i * 2]     = o0;
    o4[i * 2 + 1] = o1;
}

// ---------------------------------------------------------------------------
extern "C" void kernel_launch(void* const* d_in, const int* in_sizes, int n_in,
                              void* d_out, int out_size, void* d_ws, size_t ws_size,
                              hipStream_t stream)
{
    const float* x = (const float*)d_in[0];
    const float* W = (const float*)d_in[1];
    const float* b = (const float*)d_in[2];
    float* out = (float*)d_out;

    unsigned short* ybf = (unsigned short*)d_ws;              // 40 MB bf16 y
    float* cmat = (float*)((char*)d_ws + (48u << 20));        // 8 MB
    float* corr = cmat + (size_t)NCHUNK * 8 * N_DIM * 8;

    hipLaunchKernelGGL(k1_gemm_tanh, dim3(1024), dim3(256), 0, stream, x, W, b, ybf);
    hipLaunchKernelGGL(k2_chunks,    dim3(1024), dim3(256), 0, stream, ybf, cmat);
    hipLaunchKernelGGL(k3_combine,   dim3(8),    dim3(256), 0, stream, cmat, corr);
    hipLaunchKernelGGL(k4_final,     dim3(T_DIM * N_DIM * C_DIM / 8 / 256),
                       dim3(256), 0, stream, ybf, corr, out);
}

// Round 17
// 343.774 us; speedup vs baseline: 2.7241x; 1.0674x over previous
//
#include <hip/hip_runtime.h>
#include <hip/hip_bf16.h>

#define T_DIM 2048
#define N_DIM 256
#define K_DIM 256
#define C_DIM 40
#define CHUNK 32
#define NCHUNK 64                     // T_DIM / CHUNK
#define NSUPER (T_DIM * N_DIM / 64)   // 8192 supertiles of 64 rows

#define LOG2E_F 1.44269504088896340736f
#define LN2_F   0.69314718055994530942f
#define NEGBIG  (-1.0e30f)

typedef short bf16x8 __attribute__((ext_vector_type(8)));
typedef float f32x4  __attribute__((ext_vector_type(4)));

__device__ __forceinline__ float fexp2(float x) { return exp2f(x); }
__device__ __forceinline__ float flog2(float x) { return log2f(x); }
__device__ __forceinline__ float frcp(float x) { return __frcp_rn(x); }

__device__ __forceinline__ unsigned int pk2(float a, float b)
{
    __hip_bfloat162 h = __float22bfloat162_rn(make_float2(a, b));
    unsigned int r;
    __builtin_memcpy(&r, &h, sizeof(r));
    return r;
}

__device__ __forceinline__ uint4 pack8u(float4 lo, float4 hi)
{
    uint4 t;
    t.x = pk2(lo.x, lo.y);
    t.y = pk2(lo.z, lo.w);
    t.z = pk2(hi.x, hi.y);
    t.w = pk2(hi.z, hi.w);
    return t;
}

__device__ __forceinline__ bf16x8 as_bf16x8(uint4 u)
{
    bf16x8 r;
    __builtin_memcpy(&r, &u, sizeof(r));
    return r;
}

__device__ __forceinline__ unsigned short bf16r(float v)
{
    return (unsigned short)(pk2(v, 0.0f) & 0xffffu);
}

__device__ __forceinline__ float bl(unsigned int w) { return __uint_as_float(w << 16); }
__device__ __forceinline__ float bh(unsigned int w) { return __uint_as_float(w & 0xffff0000u); }

__device__ __forceinline__ float tanh5(float v)
{
    const float e = fexp2(fabsf(v) * (2.0f * LOG2E_F)); // e^(2|v|)
    const float t = 1.0f - 2.0f * frcp(e + 1.0f);       // tanh(|v|)
    return 5.0f * copysignf(t, v);
}

// ---------------------------------------------------------------------------
// K1: yb[row][c] = bf16(5*tanh(dot(x[row], W[c]) + b[c]))  via bf16 MFMA.
// R12's reg-staged bf16 double-buffer (16 waves/CU) + R13's sync discipline
// (raw s_barrier + lgkmcnt-only waits; NO forced vmcnt drain — R12's
// failure was __syncthreads' vmcnt(0)). Composite model from R11-R16:
// streamed BW ~ waves/CU x bytes-in-flight/wave; this gives 16 waves x
// 8KB = 128KB/CU in flight, 2x R13. Loads for tile t+1 issue at the top
// (sched_barrier-pinned), consumed at the bottom after MFMA+B1+epilogue —
// compiler's natural vmcnt waits land after the longest window.
// Math byte-identical to R9 (same swizzle; absmax-verified).
// ---------------------------------------------------------------------------
__global__ __launch_bounds__(512, 4) void k1_gemm_tanh(
    const float* __restrict__ x, const float* __restrict__ W,
    const float* __restrict__ b, unsigned short* __restrict__ yb)
{
    __shared__ __align__(16) unsigned char xl[2][64 * 512]; // 2 x 32 KB bf16 (swizzled)
    __shared__ __align__(16) float pl[4 * 12 * 64];         // 12 KB partials

    const int tid  = threadIdx.x;
    const int wave = tid >> 6;
    const int lane = tid & 63;
    const int lr   = lane & 15;
    const int kg   = lane >> 4;
    const int mt   = wave & 3;            // M-tile 0..3 (rows mt*16..+15)
    const int kh   = wave >> 2;           // K-half: ks in [kh*4, kh*4+4)

    const float bc0 = b[lr];
    const float bc1 = b[16 + lr];
    const float bc2 = (lr < 8) ? b[32 + lr] : 0.0f;

    // ---- W fragments for this wave's 4 k-slices (48 VGPR) ----
    bf16x8 wf[4][3];
#pragma unroll
    for (int i = 0; i < 4; ++i) {
        const int ks = kh * 4 + i;
#pragma unroll
        for (int nt = 0; nt < 3; ++nt) {
            const int col = nt * 16 + lr;
            float4 lo = make_float4(0, 0, 0, 0), hi = lo;
            if (col < C_DIM) {
                const float* wp = W + (size_t)col * K_DIM + ks * 32 + kg * 8;
                lo = *(const float4*)wp;
                hi = *(const float4*)(wp + 4);
            }
            wf[i][nt] = as_bf16x8(pack8u(lo, hi));
        }
    }

    // staging ds_write offsets: f4 = p*512 + tid (1 row per wave-inst, 1KB
    // contiguous global); LDS bf16 XOR-swizzled by (row&7)<<4.
    int soff[8];
#pragma unroll
    for (int p = 0; p < 8; ++p) {
        const int f4  = p * 512 + tid;
        const int row = f4 >> 6;
        const int kq  = f4 & 63;
        soff[p] = (row * 512 + kq * 8) ^ ((row & 7) << 4);
    }

    const int rbase = (mt * 16 + lr) * 512;
    const int swz   = (lr & 7) << 4;

    // ---- prologue: stage tile 0 ----
    int st = blockIdx.x;
    float4 v[8];
    {
        const float4* __restrict__ xg4 =
            (const float4*)(x + (size_t)st * 64 * K_DIM);
#pragma unroll
        for (int p = 0; p < 8; ++p) v[p] = xg4[p * 512 + tid];
#pragma unroll
        for (int p = 0; p < 8; ++p) {
            uint2 w2;
            w2.x = pk2(v[p].x, v[p].y);
            w2.y = pk2(v[p].z, v[p].w);
            *(uint2*)(xl[0] + soff[p]) = w2;
        }
    }
    asm volatile("s_waitcnt lgkmcnt(0)" ::: "memory");
    __builtin_amdgcn_s_barrier();

    int cur = 0;
#pragma unroll 1
    for (int t = 0; t < 8; ++t, st += 1024) {
        // ---- issue next tile's 8 loads FIRST; pin them above the MFMA ----
        const bool have_next = (t + 1 < 8);
        if (have_next) {
            const float4* __restrict__ xg4 =
                (const float4*)(x + (size_t)(st + 1024) * 64 * K_DIM);
#pragma unroll
            for (int p = 0; p < 8; ++p) v[p] = xg4[p * 512 + tid];
            __builtin_amdgcn_sched_barrier(0);
        }

        // ---- MFMA on xl[cur] ----
        f32x4 af0, af1, af2;
        if (kh == 0) {
            af0 = (f32x4){bc0, bc0, bc0, bc0};
            af1 = (f32x4){bc1, bc1, bc1, bc1};
            af2 = (f32x4){bc2, bc2, bc2, bc2};
        } else {
            af0 = (f32x4){0.f, 0.f, 0.f, 0.f}; af1 = af0; af2 = af0;
        }
        const unsigned char* xb = xl[cur];
#pragma unroll
        for (int i = 0; i < 4; ++i) {
            const int ks = kh * 4 + i;
            const bf16x8 a =
                *(const bf16x8*)(xb + ((rbase + ks * 64 + kg * 16) ^ swz));
            af0 = __builtin_amdgcn_mfma_f32_16x16x32_bf16(a, wf[i][0], af0, 0, 0, 0);
            af1 = __builtin_amdgcn_mfma_f32_16x16x32_bf16(a, wf[i][1], af1, 0, 0, 0);
            af2 = __builtin_amdgcn_mfma_f32_16x16x32_bf16(a, wf[i][2], af2, 0, 0, 0);
        }

        if (kh == 1) {      // publish upper-K partials: pl[mt][j][lane]
            float* p = pl + (mt * 12) * 64 + lane;
#pragma unroll
            for (int j = 0; j < 4; ++j) p[j * 64]       = af0[j];
#pragma unroll
            for (int j = 0; j < 4; ++j) p[(4 + j) * 64] = af1[j];
#pragma unroll
            for (int j = 0; j < 4; ++j) p[(8 + j) * 64] = af2[j];
        }
        asm volatile("s_waitcnt lgkmcnt(0)" ::: "memory");
        __builtin_amdgcn_s_barrier();      // B1: pl visible; xl[cur] reads done

        if (kh == 0) {     // combine + epilogue; loads still in flight
            const float* p = pl + (mt * 12) * 64 + lane;
            unsigned short* yr =
                yb + ((size_t)st * 64 + mt * 16 + kg * 4) * C_DIM;
#pragma unroll
            for (int r = 0; r < 4; ++r) {
                yr[r * C_DIM + lr]      = bf16r(tanh5(af0[r] + p[r * 64]));
                yr[r * C_DIM + 16 + lr] = bf16r(tanh5(af1[r] + p[(4 + r) * 64]));
                if (lr < 8)
                    yr[r * C_DIM + 32 + lr] = bf16r(tanh5(af2[r] + p[(8 + r) * 64]));
            }
        }

        if (have_next) {   // convert + write prefetched tile into xl[cur^1];
                           // compiler inserts the minimal vmcnt waits here
            unsigned char* xn = xl[cur ^ 1];
#pragma unroll
            for (int p = 0; p < 8; ++p) {
                uint2 w2;
                w2.x = pk2(v[p].x, v[p].y);
                w2.y = pk2(v[p].z, v[p].w);
                *(uint2*)(xn + soff[p]) = w2;
            }
        }
        asm volatile("s_waitcnt lgkmcnt(0)" ::: "memory");
        __builtin_amdgcn_s_barrier();      // B2: next tile staged
        cur ^= 1;
    }
}

// ---------------------------------------------------------------------------
// K2: per (chain n, chunk g) propagate the 8x8 log-semiring matrix through
// 32 steps; y bf16 (5 x uint4 loads, shift-unpack). Base-2 domain.
// ---------------------------------------------------------------------------
__global__ __launch_bounds__(256) void k2_chunks(
    const unsigned short* __restrict__ yb, float* __restrict__ cmat)
{
    const int tid  = threadIdx.x;
    const int wave = tid >> 6;
    const int lane = tid & 63;
    const int task = lane >> 3;   // 8 tasks per wave
    const int c    = lane & 7;    // column owned by this lane
    const int g    = blockIdx.x & (NCHUNK - 1);
    const int n    = ((blockIdx.x >> 6) << 5) + (wave << 3) + task;

    float col[8];
#pragma unroll
    for (int j = 0; j < 8; ++j) col[j] = (j == c) ? 0.0f : NEGBIG;

    const unsigned short* __restrict__ yp =
        yb + ((size_t)(g * CHUNK) * N_DIM + (size_t)n) * C_DIM;

#pragma unroll 1
    for (int s = 0; s < CHUNK; ++s) {
        float sc[C_DIM];
        const uint4* p4 = (const uint4*)yp;
#pragma unroll
        for (int q = 0; q < 5; ++q) {
            const uint4 u = p4[q];
            sc[8 * q + 0] = bl(u.x) * LOG2E_F;
            sc[8 * q + 1] = bh(u.x) * LOG2E_F;
            sc[8 * q + 2] = bl(u.y) * LOG2E_F;
            sc[8 * q + 3] = bh(u.y) * LOG2E_F;
            sc[8 * q + 4] = bl(u.z) * LOG2E_F;
            sc[8 * q + 5] = bh(u.z) * LOG2E_F;
            sc[8 * q + 6] = bl(u.w) * LOG2E_F;
            sc[8 * q + 7] = bh(u.w) * LOG2E_F;
        }
        float nc[8];
#pragma unroll
        for (int d = 0; d < 4; ++d) {          // dense rows: lse over 8
            float tv[8];
#pragma unroll
            for (int j = 0; j < 8; ++j) tv[j] = sc[d * 8 + j] + col[j];
            float m = tv[0];
#pragma unroll
            for (int j = 1; j < 8; ++j) m = fmaxf(m, tv[j]);
            float ss = 0.0f;
#pragma unroll
            for (int j = 0; j < 8; ++j) ss += fexp2(tv[j] - m);
            nc[d] = m + flog2(ss);
        }
#pragma unroll
        for (int i = 0; i < 4; ++i) {          // sparse rows: logaddexp of 2
            const float a  = sc[32 + i] + col[i];
            const float bb = sc[36 + i] + col[i + 4];
            const float m  = fmaxf(a, bb);
            const float ss = fexp2(a - m) + fexp2(bb - m);
            nc[4 + i] = m + flog2(ss);
        }
#pragma unroll
        for (int j = 0; j < 8; ++j) col[j] = nc[j];
        yp += (size_t)N_DIM * C_DIM;
    }
    // store M[j][c] at cmat[((g*8 + c)*N_DIM + n)*8 + j]
    float* __restrict__ op = cmat + (((size_t)g * 8 + c) * N_DIM + n) * 8;
#pragma unroll
    for (int j = 0; j < 8; ++j) op[j] = col[j];
}

// ---------------------------------------------------------------------------
// K3: per chain, fold the 64 chunk matrices into logZ. Widened: 32 blocks x
// 64 thr (8 chains/block) -> 4x more CUs busy than the old 8x256 split.
// ---------------------------------------------------------------------------
__global__ __launch_bounds__(64) void k3_combine(
    const float* __restrict__ cmat, float* __restrict__ corr)
{
    const int tid = threadIdx.x;
    const int d   = tid & 7;
    const int n   = blockIdx.x * 8 + (tid >> 3);

    float v[8];
#pragma unroll
    for (int j = 0; j < 8; ++j) v[j] = 0.0f;

#pragma unroll 1
    for (int g = 0; g < NCHUNK; ++g) {
        const float* mg = cmat + ((size_t)g * 8 * N_DIM + n) * 8 + d;
        float mm[8];
#pragma unroll
        for (int j = 0; j < 8; ++j) mm[j] = mg[(size_t)j * N_DIM * 8];
        float tv[8];
#pragma unroll
        for (int j = 0; j < 8; ++j) tv[j] = mm[j] + v[j];
        float m = tv[0];
#pragma unroll
        for (int j = 1; j < 8; ++j) m = fmaxf(m, tv[j]);
        float ss = 0.0f;
#pragma unroll
        for (int j = 0; j < 8; ++j) ss += fexp2(tv[j] - m);
        const float nv = m + flog2(ss);
#pragma unroll
        for (int j = 0; j < 8; ++j) v[j] = __shfl(nv, j, 8);
    }
    float m = v[0];
#pragma unroll
    for (int j = 1; j < 8; ++j) m = fmaxf(m, v[j]);
    float ss = 0.0f;
#pragma unroll
    for (int j = 0; j < 8; ++j) ss += fexp2(v[j] - m);
    const float lz2 = m + flog2(ss);                 // base-2 logZ
    if (d == 0) corr[n] = lz2 * LN2_F / (float)T_DIM;
}

// ---------------------------------------------------------------------------
// K4: out[t][n][c] = f32(yb[t][n][c]) - corr[n]
// ---------------------------------------------------------------------------
__global__ __launch_bounds__(256) void k4_final(
    const unsigned short* __restrict__ yb, const float* __restrict__ corr,
    float* __restrict__ out)
{
    const int i = blockIdx.x * 256 + threadIdx.x;    // 8-elem group index
    const uint4 u = ((const uint4*)yb)[i];
    const float cr = corr[(i / 5) & (N_DIM - 1)];    // 5 groups per row
    float4 o0, o1;
    o0.x = bl(u.x) - cr; o0.y = bh(u.x) - cr;
    o0.z = bl(u.y) - cr; o0.w = bh(u.y) - cr;
    o1.x = bl(u.z) - cr; o1.y = bh(u.z) - cr;
    o1.z = bl(u.w) - cr; o1.w = bh(u.w) - cr;
    float4* o4 = (float4*)out;
    o4[i * 2]     = o0;
    o4[i * 2 + 1] = o1;
}

// ---------------------------------------------------------------------------
extern "C" void kernel_launch(void* const* d_in, const int* in_sizes, int n_in,
                              void* d_out, int out_size, void* d_ws, size_t ws_size,
                              hipStream_t stream)
{
    const float* x = (const float*)d_in[0];
    const float* W = (const float*)d_in[1];
    const float* b = (const float*)d_in[2];
    float* out = (float*)d_out;

    unsigned short* ybf = (unsigned short*)d_ws;              // 40 MB bf16 y
    float* cmat = (float*)((char*)d_ws + (48u << 20));        // 4 MB
    float* corr = cmat + (size_t)NCHUNK * 8 * N_DIM * 8;

    hipLaunchKernelGGL(k1_gemm_tanh, dim3(1024), dim3(512), 0, stream, x, W, b, ybf);
    hipLaunchKernelGGL(k2_chunks,    dim3(512),  dim3(256), 0, stream, ybf, cmat);
    hipLaunchKernelGGL(k3_combine,   dim3(32),   dim3(64),  0, stream, cmat, corr);
    hipLaunchKernelGGL(k4_final,     dim3(T_DIM * N_DIM * C_DIM / 8 / 256),
                       dim3(256), 0, stream, ybf, corr, out);
}

// Round 18
// 274.059 us; speedup vs baseline: 3.4171x; 1.2544x over previous
//
#include <hip/hip_runtime.h>
#include <hip/hip_bf16.h>

#define T_DIM 2048
#define N_DIM 256
#define K_DIM 256
#define C_DIM 40
#define CHUNK 16
#define NCHUNK 128                    // T_DIM / CHUNK

#define LOG2E_F 1.44269504088896340736f
#define LN2_F   0.69314718055994530942f
#define NEGBIG  (-1.0e30f)

typedef short bf16x8 __attribute__((ext_vector_type(8)));
typedef float f32x4  __attribute__((ext_vector_type(4)));

__device__ __forceinline__ float fexp2(float x) { return exp2f(x); }
__device__ __forceinline__ float flog2(float x) { return log2f(x); }
__device__ __forceinline__ float frcp(float x) { return __frcp_rn(x); }

__device__ __forceinline__ unsigned int pk2(float a, float b)
{
    __hip_bfloat162 h = __float22bfloat162_rn(make_float2(a, b));
    unsigned int r;
    __builtin_memcpy(&r, &h, sizeof(r));
    return r;
}

__device__ __forceinline__ uint4 pack8u(float4 lo, float4 hi)
{
    uint4 t;
    t.x = pk2(lo.x, lo.y);
    t.y = pk2(lo.z, lo.w);
    t.z = pk2(hi.x, hi.y);
    t.w = pk2(hi.z, hi.w);
    return t;
}

__device__ __forceinline__ bf16x8 as_bf16x8(uint4 u)
{
    bf16x8 r;
    __builtin_memcpy(&r, &u, sizeof(r));
    return r;
}

__device__ __forceinline__ unsigned short bf16r(float v)
{
    return (unsigned short)(pk2(v, 0.0f) & 0xffffu);
}

__device__ __forceinline__ float bl(unsigned int w) { return __uint_as_float(w << 16); }
__device__ __forceinline__ float bh(unsigned int w) { return __uint_as_float(w & 0xffff0000u); }

__device__ __forceinline__ float tanh5(float v)
{
    const float e = fexp2(fabsf(v) * (2.0f * LOG2E_F)); // e^(2|v|)
    const float t = 1.0f - 2.0f * frcp(e + 1.0f);       // tanh(|v|)
    return 5.0f * copysignf(t, v);
}

// ---------------------------------------------------------------------------
// K1: R13 VERBATIM (best measured: ~150us; at the gload_lds structural
// ceiling — in-flight/CU = prefetch-buffer LDS <= 64KB => ~3.4 TB/s).
// global_load_lds 2-phase pipeline, counted vmcnt, both-sides unit swizzle.
// ---------------------------------------------------------------------------
__global__ __launch_bounds__(256, 2) void k1_gemm_tanh(
    const float* __restrict__ x, const float* __restrict__ W,
    const float* __restrict__ b, unsigned short* __restrict__ yb)
{
    __shared__ __align__(16) float xl[2][32 * 256];   // 2 x 32 KB fp32 (unit-swizzled)
    __shared__ __align__(16) float pl[2][12 * 64];    // 6 KB partials [mt][j*64+lane]

    const int tid  = threadIdx.x;
    const int wave = tid >> 6;
    const int lane = tid & 63;
    const int lr   = lane & 15;
    const int kg   = lane >> 4;
    const int mt   = wave & 1;    // M-tile: rows mt*16 .. +16
    const int kh   = wave >> 1;   // K-half: ks in [kh*4, kh*4+4)

    const float bc0 = b[lr];
    const float bc1 = b[16 + lr];
    const float bc2 = (lr < 8) ? b[32 + lr] : 0.0f;

    bf16x8 wf[4][3];
#pragma unroll
    for (int i = 0; i < 4; ++i) {
        const int ks = kh * 4 + i;
#pragma unroll
        for (int nt = 0; nt < 3; ++nt) {
            const int col = nt * 16 + lr;
            float4 lo = make_float4(0, 0, 0, 0), hi = lo;
            if (col < C_DIM) {
                const float* wp = W + (size_t)col * K_DIM + ks * 32 + kg * 8;
                lo = *(const float4*)wp;
                hi = *(const float4*)(wp + 4);
            }
            wf[i][nt] = as_bf16x8(pack8u(lo, hi));
        }
    }

#define STAGE(buf, st_)                                                        \
    {                                                                          \
        _Pragma("unroll")                                                      \
        for (int p = 0; p < 8; ++p) {                                          \
            const int r = wave * 8 + p;                                        \
            const float* gp = x + ((size_t)(st_) * 32 + r) * 256               \
                                + ((lane ^ (r & 7)) << 2);                     \
            __builtin_amdgcn_global_load_lds(                                  \
                (const __attribute__((address_space(1))) unsigned int*)gp,     \
                (__attribute__((address_space(3))) unsigned int*)&xl[buf][r * 256], \
                16, 0, 0);                                                     \
        }                                                                      \
    }

    const int rr = mt * 16 + lr;
    const int sw = lr & 7;

    int st = blockIdx.x;
    STAGE(0, st)
    asm volatile("s_waitcnt vmcnt(0)" ::: "memory");
    __builtin_amdgcn_s_barrier();

    int cur = 0;
#pragma unroll 1
    for (int t = 0; t < 32; ++t, st += 512) {
        if (t + 1 < 32) STAGE(cur ^ 1, st + 512)

        f32x4 af0, af1, af2;
        if (kh == 0) {
            af0 = (f32x4){bc0, bc0, bc0, bc0};
            af1 = (f32x4){bc1, bc1, bc1, bc1};
            af2 = (f32x4){bc2, bc2, bc2, bc2};
        } else {
            af0 = (f32x4){0.f, 0.f, 0.f, 0.f}; af1 = af0; af2 = af0;
        }
        const float* rowp = &xl[cur][rr * 256];
#pragma unroll
        for (int i = 0; i < 4; ++i) {
            const int u0 = (kh * 4 + i) * 8 + kg * 2;
            const float4 lo = *(const float4*)(rowp + ((u0 ^ sw) << 2));
            const float4 hi = *(const float4*)(rowp + (((u0 + 1) ^ sw) << 2));
            const bf16x8 a = as_bf16x8(pack8u(lo, hi));
            af0 = __builtin_amdgcn_mfma_f32_16x16x32_bf16(a, wf[i][0], af0, 0, 0, 0);
            af1 = __builtin_amdgcn_mfma_f32_16x16x32_bf16(a, wf[i][1], af1, 0, 0, 0);
            af2 = __builtin_amdgcn_mfma_f32_16x16x32_bf16(a, wf[i][2], af2, 0, 0, 0);
        }

        if (kh == 1) {
            float* p = &pl[mt][lane];
#pragma unroll
            for (int j = 0; j < 4; ++j) p[j * 64]       = af0[j];
#pragma unroll
            for (int j = 0; j < 4; ++j) p[(4 + j) * 64] = af1[j];
#pragma unroll
            for (int j = 0; j < 4; ++j) p[(8 + j) * 64] = af2[j];
        }
        asm volatile("s_waitcnt lgkmcnt(0)" ::: "memory");
        __builtin_amdgcn_s_barrier();      // B1: pl visible; xl[cur] reads done

        if (kh == 0) {
            const float* p = &pl[mt][lane];
            unsigned short* yr =
                yb + ((size_t)st * 32 + mt * 16 + kg * 4) * C_DIM;
#pragma unroll
            for (int r = 0; r < 4; ++r) {
                yr[r * C_DIM + lr]      = bf16r(tanh5(af0[r] + p[r * 64]));
                yr[r * C_DIM + 16 + lr] = bf16r(tanh5(af1[r] + p[(4 + r) * 64]));
                if (lr < 8)
                    yr[r * C_DIM + 32 + lr] = bf16r(tanh5(af2[r] + p[(8 + r) * 64]));
            }
            // 8 gloads are OLDEST, 12 stores newest; vmcnt retires in order:
            // <=12 outstanding  =>  all gloads landed in LDS.
            asm volatile("s_waitcnt vmcnt(12)" ::: "memory");
        } else {
            asm volatile("s_waitcnt vmcnt(0)" ::: "memory");
        }
        __builtin_amdgcn_s_barrier();      // B2: next tile fully staged
        cur ^= 1;
    }
#undef STAGE
}

// ---------------------------------------------------------------------------
// K2: per (chain n, chunk g) propagate the 8x8 log-semiring matrix through
// 16 steps (was 32): 128 chunks -> 1024 blocks = 2x wave parallelism and
// half the serial chain. Exact-equivalent math (associativity).
// ---------------------------------------------------------------------------
__global__ __launch_bounds__(256) void k2_chunks(
    const unsigned short* __restrict__ yb, float* __restrict__ cmat)
{
    const int tid  = threadIdx.x;
    const int wave = tid >> 6;
    const int lane = tid & 63;
    const int task = lane >> 3;   // 8 tasks per wave
    const int c    = lane & 7;    // column owned by this lane
    const int g    = blockIdx.x & (NCHUNK - 1);
    const int n    = ((blockIdx.x >> 7) << 5) + (wave << 3) + task;

    float col[8];
#pragma unroll
    for (int j = 0; j < 8; ++j) col[j] = (j == c) ? 0.0f : NEGBIG;

    const unsigned short* __restrict__ yp =
        yb + ((size_t)(g * CHUNK) * N_DIM + (size_t)n) * C_DIM;

#pragma unroll 1
    for (int s = 0; s < CHUNK; ++s) {
        float sc[C_DIM];
        const uint4* p4 = (const uint4*)yp;
#pragma unroll
        for (int q = 0; q < 5; ++q) {
            const uint4 u = p4[q];
            sc[8 * q + 0] = bl(u.x) * LOG2E_F;
            sc[8 * q + 1] = bh(u.x) * LOG2E_F;
            sc[8 * q + 2] = bl(u.y) * LOG2E_F;
            sc[8 * q + 3] = bh(u.y) * LOG2E_F;
            sc[8 * q + 4] = bl(u.z) * LOG2E_F;
            sc[8 * q + 5] = bh(u.z) * LOG2E_F;
            sc[8 * q + 6] = bl(u.w) * LOG2E_F;
            sc[8 * q + 7] = bh(u.w) * LOG2E_F;
        }
        float nc[8];
#pragma unroll
        for (int d = 0; d < 4; ++d) {          // dense rows: lse over 8
            float tv[8];
#pragma unroll
            for (int j = 0; j < 8; ++j) tv[j] = sc[d * 8 + j] + col[j];
            float m = tv[0];
#pragma unroll
            for (int j = 1; j < 8; ++j) m = fmaxf(m, tv[j]);
            float ss = 0.0f;
#pragma unroll
            for (int j = 0; j < 8; ++j) ss += fexp2(tv[j] - m);
            nc[d] = m + flog2(ss);
        }
#pragma unroll
        for (int i = 0; i < 4; ++i) {          // sparse rows: logaddexp of 2
            const float a  = sc[32 + i] + col[i];
            const float bb = sc[36 + i] + col[i + 4];
            const float m  = fmaxf(a, bb);
            const float ss = fexp2(a - m) + fexp2(bb - m);
            nc[4 + i] = m + flog2(ss);
        }
#pragma unroll
        for (int j = 0; j < 8; ++j) col[j] = nc[j];
        yp += (size_t)N_DIM * C_DIM;
    }
    // store M[j][c] at cmat[((g*8 + c)*N_DIM + n)*8 + j]
    float* __restrict__ op = cmat + (((size_t)g * 8 + c) * N_DIM + n) * 8;
#pragma unroll
    for (int j = 0; j < 8; ++j) op[j] = col[j];
}

// ---------------------------------------------------------------------------
// K3: per chain, fold the 128 chunk matrices into logZ. 32 blocks x 64 thr
// (8 chains/block) -> 4x more CUs busy than the old 8x256 split.
// ---------------------------------------------------------------------------
__global__ __launch_bounds__(64) void k3_combine(
    const float* __restrict__ cmat, float* __restrict__ corr)
{
    const int tid = threadIdx.x;
    const int d   = tid & 7;
    const int n   = blockIdx.x * 8 + (tid >> 3);

    float v[8];
#pragma unroll
    for (int j = 0; j < 8; ++j) v[j] = 0.0f;

#pragma unroll 1
    for (int g = 0; g < NCHUNK; ++g) {
        const float* mg = cmat + ((size_t)g * 8 * N_DIM + n) * 8 + d;
        float mm[8];
#pragma unroll
        for (int j = 0; j < 8; ++j) mm[j] = mg[(size_t)j * N_DIM * 8];
        float tv[8];
#pragma unroll
        for (int j = 0; j < 8; ++j) tv[j] = mm[j] + v[j];
        float m = tv[0];
#pragma unroll
        for (int j = 1; j < 8; ++j) m = fmaxf(m, tv[j]);
        float ss = 0.0f;
#pragma unroll
        for (int j = 0; j < 8; ++j) ss += fexp2(tv[j] - m);
        const float nv = m + flog2(ss);
#pragma unroll
        for (int j = 0; j < 8; ++j) v[j] = __shfl(nv, j, 8);
    }
    float m = v[0];
#pragma unroll
    for (int j = 1; j < 8; ++j) m = fmaxf(m, v[j]);
    float ss = 0.0f;
#pragma unroll
    for (int j = 0; j < 8; ++j) ss += fexp2(v[j] - m);
    const float lz2 = m + flog2(ss);                 // base-2 logZ
    if (d == 0) corr[n] = lz2 * LN2_F / (float)T_DIM;
}

// ---------------------------------------------------------------------------
// K4: out[t][n][c] = f32(yb[t][n][c]) - corr[n]
// ---------------------------------------------------------------------------
__global__ __launch_bounds__(256) void k4_final(
    const unsigned short* __restrict__ yb, const float* __restrict__ corr,
    float* __restrict__ out)
{
    const int i = blockIdx.x * 256 + threadIdx.x;    // 8-elem group index
    const uint4 u = ((const uint4*)yb)[i];
    const float cr = corr[(i / 5) & (N_DIM - 1)];    // 5 groups per row
    float4 o0, o1;
    o0.x = bl(u.x) - cr; o0.y = bh(u.x) - cr;
    o0.z = bl(u.y) - cr; o0.w = bh(u.y) - cr;
    o1.x = bl(u.z) - cr; o1.y = bh(u.z) - cr;
    o1.z = bl(u.w) - cr; o1.w = bh(u.w) - cr;
    float4* o4 = (float4*)out;
    o4[i * 2]     = o0;
    o4[i * 2 + 1] = o1;
}

// ---------------------------------------------------------------------------
extern "C" void kernel_launch(void* const* d_in, const int* in_sizes, int n_in,
                              void* d_out, int out_size, void* d_ws, size_t ws_size,
                              hipStream_t stream)
{
    const float* x = (const float*)d_in[0];
    const float* W = (const float*)d_in[1];
    const float* b = (const float*)d_in[2];
    float* out = (float*)d_out;

    unsigned short* ybf = (unsigned short*)d_ws;              // 40 MB bf16 y
    float* cmat = (float*)((char*)d_ws + (48u << 20));        // 8 MB
    float* corr = cmat + (size_t)NCHUNK * 8 * N_DIM * 8;

    hipLaunchKernelGGL(k1_gemm_tanh, dim3(512),  dim3(256), 0, stream, x, W, b, ybf);
    hipLaunchKernelGGL(k2_chunks,    dim3(1024), dim3(256), 0, stream, ybf, cmat);
    hipLaunchKernelGGL(k3_combine,   dim3(32),   dim3(64),  0, stream, cmat, corr);
    hipLaunchKernelGGL(k4_final,     dim3(T_DIM * N_DIM * C_DIM / 8 / 256),
                       dim3(256), 0, stream, ybf, corr, out);
}